// Round 1
// baseline (83.209 us; speedup 1.0000x reference)
//
#include <hip/hip_runtime.h>

// Problem constants (match reference)
constexpr int B = 32, T = 512, F = 300, S = 256, KMAX = 32;
constexpr int T_PER_BLOCK = 16;   // t-values handled per block

// out[b,t,s] = count of k with thresholds[s,k] <= features[b,t,slot_ids[s]]
// (valid rows sorted ascending, invalid entries are +inf -> never counted)
__global__ __launch_bounds__(256, 4) void SequenceBucketPreprocessor_kernel(
    const float* __restrict__ features,    // (B,T,F)
    const float* __restrict__ thresholds,  // (S,KMAX)
    const int*   __restrict__ slot_ids,    // (S,)
    int*         __restrict__ out)         // (B,T,S) int32
{
    const int s   = threadIdx.x;                 // one s per thread (S==256==blockDim)
    const int bt0 = blockIdx.x * T_PER_BLOCK;    // first flattened (b*T+t) index

    // This thread's 32 thresholds -> registers (one-time, 128B/lane, L2-hot)
    float thr[KMAX];
    const float4* trow = reinterpret_cast<const float4*>(thresholds + s * KMAX);
    #pragma unroll
    for (int q = 0; q < KMAX / 4; ++q) {
        float4 v = trow[q];
        thr[q * 4 + 0] = v.x;
        thr[q * 4 + 1] = v.y;
        thr[q * 4 + 2] = v.z;
        thr[q * 4 + 3] = v.w;
    }
    const int slot = slot_ids[s];

    #pragma unroll
    for (int j = 0; j < T_PER_BLOCK; j += 4) {
        const int bt = bt0 + j;
        // 4 independent gathers (same slot, consecutive t) for load ILP
        const float v0 = features[(bt + 0) * F + slot];
        const float v1 = features[(bt + 1) * F + slot];
        const float v2 = features[(bt + 2) * F + slot];
        const float v3 = features[(bt + 3) * F + slot];

        int c0 = 0, c1 = 0, c2 = 0, c3 = 0;
        #pragma unroll
        for (int k = 0; k < KMAX; ++k) {
            c0 += (thr[k] <= v0);
            c1 += (thr[k] <= v1);
            c2 += (thr[k] <= v2);
            c3 += (thr[k] <= v3);
        }

        // coalesced int32 stores along s
        out[(bt + 0) * S + s] = c0;
        out[(bt + 1) * S + s] = c1;
        out[(bt + 2) * S + s] = c2;
        out[(bt + 3) * S + s] = c3;
    }
}

extern "C" void kernel_launch(void* const* d_in, const int* in_sizes, int n_in,
                              void* d_out, int out_size, void* d_ws, size_t ws_size,
                              hipStream_t stream) {
    const float* features   = (const float*)d_in[0];  // (B,T,F) f32
    const float* thresholds = (const float*)d_in[1];  // (S,KMAX) f32
    const int*   slot_ids   = (const int*)d_in[2];    // (S,) i32
    // d_in[3] = bucket_nums: not needed (encoded in +inf padding of thresholds)
    int* out = (int*)d_out;                            // (B,T,S) i32

    const int n_bt   = B * T;                          // 16384
    const int blocks = n_bt / T_PER_BLOCK;             // 1024
    SequenceBucketPreprocessor_kernel<<<dim3(blocks), dim3(S), 0, stream>>>(
        features, thresholds, slot_ids, out);
}